// Round 1
// baseline (50.543 us; speedup 1.0000x reference)
//
#include <hip/hip_runtime.h>
#include <hip/hip_bf16.h>

// Problem constants
// B=8, G=2048, K=32, N=6, C=64; fourier_B is (7,32)
// out: (B, 128, G) float32

__global__ __launch_bounds__(256) void line_pass1(
    const float* __restrict__ lc_x,     // (B,G,64)
    const float* __restrict__ knn_x,    // (B,G,32,6)
    const float* __restrict__ fB,       // (7,32)
    float* __restrict__ out)            // (B,128,G)
{
    const int wave = threadIdx.x >> 6;          // 0..3
    const int lane = threadIdx.x & 63;
    const int bg   = blockIdx.x * 4 + wave;     // 0..16383  (b*2048+g)
    const int b    = bg >> 11;
    const int g    = bg & 2047;
    const int jj   = lane & 31;

    // fourier_B column for this lane's channel
    float fb0 = fB[0*32 + jj];
    float fb1 = fB[1*32 + jj];
    float fb2 = fB[2*32 + jj];
    float fb3 = fB[3*32 + jj];
    float fb4 = fB[4*32 + jj];
    float fb5 = fB[5*32 + jj];
    float fb6 = fB[6*32 + jj];

    // ---- lc_line: normalize lc_x[b,g,:] over C=64 (one element per lane)
    const float lc = lc_x[(size_t)bg * 64 + lane];
    float ss = lc * lc;
    #pragma unroll
    for (int off = 32; off; off >>= 1) ss += __shfl_xor(ss, off, 64);
    const float lcline = lc / sqrtf(ss);

    // lc_normal = raw lc_x[3:6] (broadcast from lanes 3..5)
    const float n0 = __shfl(lc, 3, 64);
    const float n1 = __shfl(lc, 4, 64);
    const float n2 = __shfl(lc, 5, 64);

    // ---- per-lane neighbor line vector (lane&31 owns k = lane&31)
    const int k = lane & 31;
    const float* kp = knn_x + (size_t)bg * 192 + k * 6;
    const float p0 = kp[3];
    const float p1 = kp[4];
    const float p2 = kp[5];
    // cross = p x n
    const float c0 = p1 * n2 - p2 * n1;
    const float c1 = p2 * n0 - p0 * n2;
    const float c2 = p0 * n1 - p1 * n0;
    const float dt = p0 * n0 + p1 * n1 + p2 * n2;

    // lanes >= 32 compute cos channels: cos(2*pi*x) = sin(2*pi*(x+0.25))
    const float shift = (lane >= 32) ? 0.25f : 0.0f;

    float acc = 0.0f;
    #pragma unroll
    for (int kk = 0; kk < 32; ++kk) {
        // broadcast line vector of neighbor kk (compile-time lane -> v_readlane)
        const float l0 = __shfl(p0, kk, 64);
        const float l1 = __shfl(p1, kk, 64);
        const float l2 = __shfl(p2, kk, 64);
        const float l3 = __shfl(c0, kk, 64);
        const float l4 = __shfl(c1, kk, 64);
        const float l5 = __shfl(c2, kk, 64);
        const float l6 = __shfl(dt, kk, 64);

        float x = fb0 * l0;
        x = fmaf(fb1, l1, x);
        x = fmaf(fb2, l2, x);
        x = fmaf(fb3, l3, x);
        x = fmaf(fb4, l4, x);
        x = fmaf(fb5, l5, x);
        x = fmaf(fb6, l6, x);

        float t = x + shift;
        t = t - floorf(t);                       // fract -> [0,1)
        const float s  = __builtin_amdgcn_sinf(t); // sin(2*pi*t), input in revolutions
        const float s2 = s * s;
        acc = fmaf(s2 * s2, s, acc);             // acc += s^5
    }

    // kl_raw = 2 * mean_k = acc / 16
    const float klraw = acc * 0.0625f;

    const size_t obase = ((size_t)b * 128) * 2048 + g;
    out[obase + (size_t)lane * 2048]        = klraw;   // temp, normalized in pass 2
    out[obase + (size_t)(64 + lane) * 2048] = lcline;  // final
}

__global__ __launch_bounds__(256) void line_pass2(float* __restrict__ out)
{
    const int b = blockIdx.x >> 6;   // 0..7
    const int c = blockIdx.x & 63;   // 0..63
    float*       kl = out + ((size_t)b * 128 + c) * 2048;
    const float* ll = out + ((size_t)b * 128 + 64 + c) * 2048;

    float v[8];
    float ss = 0.0f;
    #pragma unroll
    for (int i = 0; i < 8; ++i) {
        v[i] = kl[threadIdx.x + i * 256];
        ss = fmaf(v[i], v[i], ss);
    }
    #pragma unroll
    for (int off = 32; off; off >>= 1) ss += __shfl_xor(ss, off, 64);

    __shared__ float wsum[4];
    if ((threadIdx.x & 63) == 0) wsum[threadIdx.x >> 6] = ss;
    __syncthreads();
    const float tot = wsum[0] + wsum[1] + wsum[2] + wsum[3];
    const float rn  = 1.0f / sqrtf(tot);

    #pragma unroll
    for (int i = 0; i < 8; ++i) {
        const int idx = threadIdx.x + i * 256;
        kl[idx] = fmaf(v[i], rn, -ll[idx]);
    }
}

extern "C" void kernel_launch(void* const* d_in, const int* in_sizes, int n_in,
                              void* d_out, int out_size, void* d_ws, size_t ws_size,
                              hipStream_t stream) {
    const float* lc_x  = (const float*)d_in[0];   // 8*2048*64
    const float* knn_x = (const float*)d_in[1];   // 8*2048*32*6
    const float* fB    = (const float*)d_in[2];   // 7*32
    float* out = (float*)d_out;                   // 8*128*2048

    line_pass1<<<4096, 256, 0, stream>>>(lc_x, knn_x, fB, out);
    line_pass2<<<512, 256, 0, stream>>>(out);
}

// Round 2
// 37.166 us; speedup vs baseline: 1.3599x; 1.3599x over previous
//
#include <hip/hip_runtime.h>
#include <hip/hip_bf16.h>

// Problem constants: B=8, G=2048, K=32, N=6, C=64; fourier_B is (7,32)
// out: (B, 128, G) float32
//
// Algebraic simplification (validated round 1): up/down == mean_k(knn_f)
// since e_x is constant over k, so kl_raw = 2*mean_k(sin^5/cos^5(2*pi*x)).

#if __has_builtin(__builtin_amdgcn_fractf)
  #define FRACT(x) __builtin_amdgcn_fractf(x)
#else
  #define FRACT(x) ((x) - floorf(x))
#endif

// One wave (64 threads) per (b,g). All knn/normal data is workgroup-uniform
// (address depends only on blockIdx) -> scalar loads, no shuffles, no LDS.
__global__ __launch_bounds__(64) void line_pass1(
    const float* __restrict__ lc_x,     // (B,G,64)
    const float* __restrict__ knn_x,    // (B,G,32,6)
    const float* __restrict__ fB,       // (7,32)
    float* __restrict__ out)            // (B,128,G)
{
    const int lane = threadIdx.x;               // 0..63
    const int bg   = blockIdx.x;                // 0..16383
    const int b    = bg >> 11;
    const int g    = bg & 2047;
    const int jj   = lane & 31;

    // fourier_B column for this lane's channel (per-lane vector loads)
    const float fb0 = fB[0*32 + jj];
    const float fb1 = fB[1*32 + jj];
    const float fb2 = fB[2*32 + jj];
    const float fb3 = fB[3*32 + jj];
    const float fb4 = fB[4*32 + jj];
    const float fb5 = fB[5*32 + jj];
    const float fb6 = fB[6*32 + jj];

    // ---- lc_line: normalize lc_x[b,g,:] over C=64 (one element per lane)
    const float* lcr = lc_x + (size_t)bg * 64;
    const float lc = lcr[lane];
    float ssum = lc * lc;
    #pragma unroll
    for (int off = 32; off; off >>= 1) ssum += __shfl_xor(ssum, off, 64);
    const float lcline = lc / sqrtf(ssum);

    // lc_normal = raw lc_x[3:6] — uniform address -> scalar load (SGPR)
    const float n0 = lcr[3];
    const float n1 = lcr[4];
    const float n2 = lcr[5];

    // knn row base — uniform address
    const float* kp = knn_x + (size_t)bg * 192;

    // lanes >= 32 compute cos channels: cos(2*pi*x) = sin(2*pi*(x+0.25))
    const float shift = (lane >= 32) ? 0.25f : 0.0f;

    float acc[4] = {0.0f, 0.0f, 0.0f, 0.0f};
    #pragma unroll
    for (int k = 0; k < 32; ++k) {
        // uniform scalar loads (s_load): neighbor point p = knn_x[...,3:6]
        const float p0 = kp[k * 6 + 3];
        const float p1 = kp[k * 6 + 4];
        const float p2 = kp[k * 6 + 5];
        // cross = p x n, dot = p . n  (wave-uniform values, redundant per lane)
        const float c0 = fmaf(p1, n2, -p2 * n1);
        const float c1 = fmaf(p2, n0, -p0 * n2);
        const float c2 = fmaf(p0, n1, -p1 * n0);
        const float dt = fmaf(p0, n0, fmaf(p1, n1, p2 * n2));

        float x = fmaf(fb0, p0, fmaf(fb1, p1, fb2 * p2));
        x = fmaf(fb3, c0, x);
        x = fmaf(fb4, c1, x);
        x = fmaf(fb5, c2, x);
        x = fmaf(fb6, dt, x);

        const float t = FRACT(x + shift);            // revolutions in [0,1)
        const float s = __builtin_amdgcn_sinf(t);    // sin(2*pi*t)
        const float s2 = s * s;
        acc[k & 3] = fmaf(s2 * s2, s, acc[k & 3]);   // += s^5  (4 chains for ILP)
    }

    // kl_raw = 2 * mean_k = sum / 16
    const float klraw = ((acc[0] + acc[1]) + (acc[2] + acc[3])) * 0.0625f;

    const size_t obase = ((size_t)b * 128) * 2048 + g;
    out[obase + (size_t)lane * 2048]        = klraw;   // normalized in pass 2
    out[obase + (size_t)(64 + lane) * 2048] = lcline;  // final
}

__global__ __launch_bounds__(256) void line_pass2(float* __restrict__ out)
{
    const int b = blockIdx.x >> 6;   // 0..7
    const int c = blockIdx.x & 63;   // 0..63
    float*       kl = out + ((size_t)b * 128 + c) * 2048;
    const float* ll = out + ((size_t)b * 128 + 64 + c) * 2048;

    float v[8];
    float ss = 0.0f;
    #pragma unroll
    for (int i = 0; i < 8; ++i) {
        v[i] = kl[threadIdx.x + i * 256];
        ss = fmaf(v[i], v[i], ss);
    }
    #pragma unroll
    for (int off = 32; off; off >>= 1) ss += __shfl_xor(ss, off, 64);

    __shared__ float wsum[4];
    if ((threadIdx.x & 63) == 0) wsum[threadIdx.x >> 6] = ss;
    __syncthreads();
    const float tot = wsum[0] + wsum[1] + wsum[2] + wsum[3];
    const float rn  = 1.0f / sqrtf(tot);

    #pragma unroll
    for (int i = 0; i < 8; ++i) {
        const int idx = threadIdx.x + i * 256;
        kl[idx] = fmaf(v[i], rn, -ll[idx]);
    }
}

extern "C" void kernel_launch(void* const* d_in, const int* in_sizes, int n_in,
                              void* d_out, int out_size, void* d_ws, size_t ws_size,
                              hipStream_t stream) {
    const float* lc_x  = (const float*)d_in[0];   // 8*2048*64
    const float* knn_x = (const float*)d_in[1];   // 8*2048*32*6
    const float* fB    = (const float*)d_in[2];   // 7*32
    float* out = (float*)d_out;                   // 8*128*2048

    line_pass1<<<16384, 64, 0, stream>>>(lc_x, knn_x, fB, out);
    line_pass2<<<512, 256, 0, stream>>>(out);
}

// Round 3
// 27.752 us; speedup vs baseline: 1.8213x; 1.3392x over previous
//
#include <hip/hip_runtime.h>
#include <hip/hip_bf16.h>

// Problem constants: B=8, G=2048, K=32, N=6, C=64; fourier_B is (7,32)
// out: (B, 128, G) float32
//
// Algebraic simplification (validated): up/down == mean_k(knn_f) since e_x is
// constant over k, so kl_raw = 2*mean_k(sin^5/cos^5(2*pi*x)).

#if __has_builtin(__builtin_amdgcn_fractf)
  #define FRACT(x) __builtin_amdgcn_fractf(x)
#else
  #define FRACT(x) ((x) - floorf(x))
#endif

// 4 waves/block, one (b,g) per wave. XCD-swizzled grid so each XCD owns a
// contiguous bg range (write-line merging in its private L2).
__global__ __launch_bounds__(256) void line_pass1(
    const float* __restrict__ lc_x,     // (B,G,64)
    const float* __restrict__ knn_x,    // (B,G,32,6)
    const float* __restrict__ fB,       // (7,32)
    float* __restrict__ out)            // (B,128,G)
{
    const int wave = threadIdx.x >> 6;
    const int lane = threadIdx.x & 63;
    // bijective XCD swizzle: 4096 blocks, 8 XCDs, 512 blocks each
    const int sbid = (blockIdx.x & 7) * 512 + (blockIdx.x >> 3);
    const int bg   = sbid * 4 + wave;           // 0..16383
    const int b    = bg >> 11;
    const int g    = bg & 2047;
    const int jj   = lane & 31;

    // fourier_B column for this lane's channel
    const float fb0 = fB[0*32 + jj];
    const float fb1 = fB[1*32 + jj];
    const float fb2 = fB[2*32 + jj];
    const float fb3 = fB[3*32 + jj];
    const float fb4 = fB[4*32 + jj];
    const float fb5 = fB[5*32 + jj];
    const float fb6 = fB[6*32 + jj];

    // ---- lc_line: normalize lc_x[b,g,:] over C=64 (one element per lane)
    const float* lcr = lc_x + (size_t)bg * 64;
    const float lc = lcr[lane];
    float ssum = lc * lc;
    #pragma unroll
    for (int off = 32; off; off >>= 1) ssum += __shfl_xor(ssum, off, 64);
    const float lcline = lc / sqrtf(ssum);

    // lc_normal = raw lc_x[3:6] (uniform address -> scalar loads)
    const float n0 = lcr[3];
    const float n1 = lcr[4];
    const float n2 = lcr[5];

    // ---- per-lane neighbor k = lane&31: load p, compute cross/dot once
    const int k = lane & 31;
    const float* kp = knn_x + (size_t)bg * 192 + k * 6;
    const float p0 = kp[3];
    const float p1 = kp[4];
    const float p2 = kp[5];
    const float c0 = fmaf(p1, n2, -p2 * n1);
    const float c1 = fmaf(p2, n0, -p0 * n2);
    const float c2 = fmaf(p0, n1, -p1 * n0);
    const float dt = fmaf(p0, n0, fmaf(p1, n1, p2 * n2));

    // stage padded 8-float line vectors in LDS: lv[wave][k] = {p0,p1,p2,c0,c1,c2,dt,0}
    __shared__ __align__(16) float lv[4][32][8];
    if (lane < 32) {
        float4 w0 = make_float4(p0, p1, p2, c0);
        *(float4*)&lv[wave][k][0] = w0;
    } else {
        float4 w1 = make_float4(c1, c2, dt, 0.0f);
        *(float4*)&lv[wave][k][4] = w1;
    }
    __syncthreads();

    // lanes >= 32 compute cos channels: cos(2*pi*x) = sin(2*pi*(x+0.25))
    const float shift = (lane >= 32) ? 0.25f : 0.0f;

    float acc[4] = {0.0f, 0.0f, 0.0f, 0.0f};
    #pragma unroll
    for (int kk = 0; kk < 32; ++kk) {
        // uniform-address LDS reads (broadcast, compile-time offsets)
        const float4 a = *(const float4*)&lv[wave][kk][0];
        const float4 c = *(const float4*)&lv[wave][kk][4];
        float x = fmaf(fb0, a.x, fmaf(fb1, a.y, fb2 * a.z));
        x = fmaf(fb3, a.w, x);
        x = fmaf(fb4, c.x, x);
        x = fmaf(fb5, c.y, x);
        x = fmaf(fb6, c.z, x);

        const float t = FRACT(x + shift);            // revolutions in [0,1)
        const float s = __builtin_amdgcn_sinf(t);    // sin(2*pi*t)
        const float s2 = s * s;
        acc[kk & 3] = fmaf(s2 * s2, s, acc[kk & 3]); // += s^5 (4 chains for ILP)
    }

    // kl_raw = 2 * mean_k = sum / 16
    const float klraw = ((acc[0] + acc[1]) + (acc[2] + acc[3])) * 0.0625f;

    const size_t obase = ((size_t)b * 128) * 2048 + g;
    out[obase + (size_t)lane * 2048]        = klraw;   // normalized in pass 2
    out[obase + (size_t)(64 + lane) * 2048] = lcline;  // final
}

__global__ __launch_bounds__(256) void line_pass2(float* __restrict__ out)
{
    const int b = blockIdx.x >> 6;   // 0..7
    const int c = blockIdx.x & 63;   // 0..63
    float*       kl = out + ((size_t)b * 128 + c) * 2048;
    const float* ll = out + ((size_t)b * 128 + 64 + c) * 2048;

    float v[8];
    float ss = 0.0f;
    #pragma unroll
    for (int i = 0; i < 8; ++i) {
        v[i] = kl[threadIdx.x + i * 256];
        ss = fmaf(v[i], v[i], ss);
    }
    #pragma unroll
    for (int off = 32; off; off >>= 1) ss += __shfl_xor(ss, off, 64);

    __shared__ float wsum[4];
    if ((threadIdx.x & 63) == 0) wsum[threadIdx.x >> 6] = ss;
    __syncthreads();
    const float tot = wsum[0] + wsum[1] + wsum[2] + wsum[3];
    const float rn  = 1.0f / sqrtf(tot);

    #pragma unroll
    for (int i = 0; i < 8; ++i) {
        const int idx = threadIdx.x + i * 256;
        kl[idx] = fmaf(v[i], rn, -ll[idx]);
    }
}

extern "C" void kernel_launch(void* const* d_in, const int* in_sizes, int n_in,
                              void* d_out, int out_size, void* d_ws, size_t ws_size,
                              hipStream_t stream) {
    const float* lc_x  = (const float*)d_in[0];   // 8*2048*64
    const float* knn_x = (const float*)d_in[1];   // 8*2048*32*6
    const float* fB    = (const float*)d_in[2];   // 7*32
    float* out = (float*)d_out;                   // 8*128*2048

    line_pass1<<<4096, 256, 0, stream>>>(lc_x, knn_x, fB, out);
    line_pass2<<<512, 256, 0, stream>>>(out);
}

// Round 5
// 26.231 us; speedup vs baseline: 1.9269x; 1.0580x over previous
//
#include <hip/hip_runtime.h>
#include <hip/hip_bf16.h>

// Problem constants: B=8, G=2048, K=32, N=6, C=64; fourier_B is (7,32)
// out: (B, 128, G) float32
//
// Algebraic simplification (validated): up/down == mean_k(knn_f) since e_x is
// constant over k, so kl_raw = 2*mean_k(sin^5/cos^5(2*pi*x)).
//
// Work split: lane = (half, jj); half=0 -> even k, half=1 -> odd k.
// Each lane computes x(jj,k) ONCE and both sin^5 and cos^5 from it
// (cos(2pi x) = sin(2pi(x+0.25))), halving the k-loop trip count and LDS reads.

#if __has_builtin(__builtin_amdgcn_fractf)
  #define FRACT(x) __builtin_amdgcn_fractf(x)
#else
  #define FRACT(x) ((x) - floorf(x))
#endif

__global__ __launch_bounds__(256) void line_pass1(
    const float* __restrict__ lc_x,     // (B,G,64)
    const float* __restrict__ knn_x,    // (B,G,32,6)
    const float* __restrict__ fB,       // (7,32)
    float* __restrict__ out)            // (B,128,G)
{
    const int wave = threadIdx.x >> 6;
    const int lane = threadIdx.x & 63;
    const int half = lane >> 5;                 // 0: even k, 1: odd k
    const int jj   = lane & 31;                 // channel
    // bijective XCD swizzle: 4096 blocks, 8 XCDs, 512 blocks each
    const int sbid = (blockIdx.x & 7) * 512 + (blockIdx.x >> 3);
    const int bg   = sbid * 4 + wave;           // 0..16383
    const int b    = bg >> 11;
    const int g    = bg & 2047;

    // fourier_B column for this lane's channel
    const float fb0 = fB[0*32 + jj];
    const float fb1 = fB[1*32 + jj];
    const float fb2 = fB[2*32 + jj];
    const float fb3 = fB[3*32 + jj];
    const float fb4 = fB[4*32 + jj];
    const float fb5 = fB[5*32 + jj];
    const float fb6 = fB[6*32 + jj];

    // ---- lc_line: normalize lc_x[b,g,:] over C=64 (one element per lane)
    const float* lcr = lc_x + (size_t)bg * 64;
    const float lc = lcr[lane];
    float ssum = lc * lc;
    #pragma unroll
    for (int off = 32; off; off >>= 1) ssum += __shfl_xor(ssum, off, 64);
    const float lcline = lc / sqrtf(ssum);

    // lc_normal = raw lc_x[3:6] (uniform address -> scalar loads)
    const float n0 = lcr[3];
    const float n1 = lcr[4];
    const float n2 = lcr[5];

    // ---- per-lane neighbor k = lane&31: load p, compute cross/dot once
    const int k = jj;
    const float* kp = knn_x + (size_t)bg * 192 + k * 6;
    const float p0 = kp[3];
    const float p1 = kp[4];
    const float p2 = kp[5];
    const float c0 = fmaf(p1, n2, -p2 * n1);
    const float c1 = fmaf(p2, n0, -p0 * n2);
    const float c2 = fmaf(p0, n1, -p1 * n0);
    const float dt = fmaf(p0, n0, fmaf(p1, n1, p2 * n2));

    // stage padded 8-float line vectors in LDS: lv[wave][k] = {p0,p1,p2,c0,c1,c2,dt,0}
    __shared__ __align__(16) float lv[4][32][8];
    if (half == 0) {
        *(float4*)&lv[wave][k][0] = make_float4(p0, p1, p2, c0);
    } else {
        *(float4*)&lv[wave][k][4] = make_float4(c1, c2, dt, 0.0f);
    }
    // producer and consumer are the same wave -> no block barrier needed
    asm volatile("s_waitcnt lgkmcnt(0)" ::: "memory");

    float accS[2] = {0.0f, 0.0f};   // sin^5 partial sums (this lane's k-subset)
    float accC[2] = {0.0f, 0.0f};   // cos^5 partial sums
    // lane (half,jj) handles k = 2*i + half ; entry stride is 8 floats per k
    const float* myk = &lv[wave][half][0];
    #pragma unroll
    for (int i = 0; i < 16; ++i) {
        const float4 a = *(const float4*)(myk + i * 16 + 0);
        const float4 c = *(const float4*)(myk + i * 16 + 4);
        float x = fmaf(fb0, a.x, fmaf(fb1, a.y, fb2 * a.z));
        x = fmaf(fb3, a.w, x);
        x = fmaf(fb4, c.x, x);
        x = fmaf(fb5, c.y, x);
        x = fmaf(fb6, c.z, x);

        const float ts = FRACT(x);                    // revolutions in [0,1)
        const float tc = FRACT(x + 0.25f);
        const float s  = __builtin_amdgcn_sinf(ts);   // sin(2*pi*x)
        const float cc = __builtin_amdgcn_sinf(tc);   // cos(2*pi*x)
        const float s2 = s * s,  s4 = s2 * s2;
        const float q2 = cc * cc, q4 = q2 * q2;
        accS[i & 1] = fmaf(s4, s,  accS[i & 1]);      // += sin^5
        accC[i & 1] = fmaf(q4, cc, accC[i & 1]);      // += cos^5
    }

    // merge even-k / odd-k halves across the lane32 boundary
    const float aS = accS[0] + accS[1];
    const float aC = accC[0] + accC[1];
    const float totS = aS + __shfl_xor(aS, 32, 64);
    const float totC = aC + __shfl_xor(aC, 32, 64);
    // lane jj -> sin channel jj ; lane 32+jj -> cos channel 32+jj
    const float klraw = (half ? totC : totS) * 0.0625f;  // 2 * mean_k

    const size_t obase = ((size_t)b * 128) * 2048 + g;
    out[obase + (size_t)lane * 2048]        = klraw;   // normalized in pass 2
    out[obase + (size_t)(64 + lane) * 2048] = lcline;  // final
}

__global__ __launch_bounds__(256) void line_pass2(float* __restrict__ out)
{
    const int b = blockIdx.x >> 6;   // 0..7
    const int c = blockIdx.x & 63;   // 0..63
    float*       kl = out + ((size_t)b * 128 + c) * 2048;
    const float* ll = out + ((size_t)b * 128 + 64 + c) * 2048;

    float v[8];
    float ss = 0.0f;
    #pragma unroll
    for (int i = 0; i < 8; ++i) {
        v[i] = kl[threadIdx.x + i * 256];
        ss = fmaf(v[i], v[i], ss);
    }
    #pragma unroll
    for (int off = 32; off; off >>= 1) ss += __shfl_xor(ss, off, 64);

    __shared__ float wsum[4];
    if ((threadIdx.x & 63) == 0) wsum[threadIdx.x >> 6] = ss;
    __syncthreads();
    const float tot = wsum[0] + wsum[1] + wsum[2] + wsum[3];
    const float rn  = 1.0f / sqrtf(tot);

    #pragma unroll
    for (int i = 0; i < 8; ++i) {
        const int idx = threadIdx.x + i * 256;
        kl[idx] = fmaf(v[i], rn, -ll[idx]);
    }
}

extern "C" void kernel_launch(void* const* d_in, const int* in_sizes, int n_in,
                              void* d_out, int out_size, void* d_ws, size_t ws_size,
                              hipStream_t stream) {
    const float* lc_x  = (const float*)d_in[0];   // 8*2048*64
    const float* knn_x = (const float*)d_in[1];   // 8*2048*32*6
    const float* fB    = (const float*)d_in[2];   // 7*32
    float* out = (float*)d_out;                   // 8*128*2048

    line_pass1<<<4096, 256, 0, stream>>>(lc_x, knn_x, fB, out);
    line_pass2<<<512, 256, 0, stream>>>(out);
}

// Round 6
// 23.808 us; speedup vs baseline: 2.1230x; 1.1018x over previous
//
#include <hip/hip_runtime.h>
#include <hip/hip_bf16.h>

// Problem constants: B=8, G=2048, K=32, N=6, C=64; fourier_B is (7,32)
// out: (B, 128, G) float32
//
// Algebraic simplifications (validated):
//  1) up/down == mean_k(knn_f) since e_x is constant over k, so
//     kl_raw = 2*mean_k(sin^5/cos^5(2*pi*x)).
//  2) x = fB . [p, p x n, p.n] is linear in p:
//     x = e0*p0 + e1*p1 + e2*p2  with per-channel e precomputed from fB and n.
//
// Work split: lane = (half, jj); half=0 -> even k, half=1 -> odd k.
// Each lane computes x(jj,k) once and both sin^5 and cos^5 from it
// (cos(2pi x) = sin(2pi(x+0.25))).

#if __has_builtin(__builtin_amdgcn_fractf)
  #define FRACT(x) __builtin_amdgcn_fractf(x)
#else
  #define FRACT(x) ((x) - floorf(x))
#endif

__global__ __launch_bounds__(256, 8) void line_pass1(
    const float* __restrict__ lc_x,     // (B,G,64)
    const float* __restrict__ knn_x,    // (B,G,32,6)
    const float* __restrict__ fB,       // (7,32)
    float* __restrict__ out)            // (B,128,G)
{
    const int wave = threadIdx.x >> 6;
    const int lane = threadIdx.x & 63;
    const int half = lane >> 5;                 // 0: even k, 1: odd k
    const int jj   = lane & 31;                 // channel
    // bijective XCD swizzle: 4096 blocks, 8 XCDs, 512 blocks each
    const int sbid = (blockIdx.x & 7) * 512 + (blockIdx.x >> 3);
    const int bg   = sbid * 4 + wave;           // 0..16383
    const int b    = bg >> 11;
    const int g    = bg & 2047;

    // fourier_B column for this lane's channel (dead after e is computed)
    const float fb0 = fB[0*32 + jj];
    const float fb1 = fB[1*32 + jj];
    const float fb2 = fB[2*32 + jj];
    const float fb3 = fB[3*32 + jj];
    const float fb4 = fB[4*32 + jj];
    const float fb5 = fB[5*32 + jj];
    const float fb6 = fB[6*32 + jj];

    // ---- lc_line: normalize lc_x[b,g,:] over C=64 (one element per lane)
    const float* lcr = lc_x + (size_t)bg * 64;
    const float lc = lcr[lane];
    float ssum = lc * lc;
    #pragma unroll
    for (int off = 32; off; off >>= 1) ssum += __shfl_xor(ssum, off, 64);
    const float lcline = lc / sqrtf(ssum);

    // lc_normal = raw lc_x[3:6] (uniform address -> scalar loads)
    const float n0 = lcr[3];
    const float n1 = lcr[4];
    const float n2 = lcr[5];

    // effective projection vector: x = e0*p0 + e1*p1 + e2*p2
    const float e0 = fmaf(fb6, n0, fmaf(fb5,  n1, fmaf(fb4, -n2, fb0)));
    const float e1 = fmaf(fb6, n1, fmaf(fb5, -n0, fmaf(fb3,  n2, fb1)));
    const float e2 = fmaf(fb6, n2, fmaf(fb4,  n0, fmaf(fb3, -n1, fb2)));

    // ---- stage p-vectors in LDS (only lanes 0-31 load/stage)
    __shared__ __align__(16) float4 lv[4][32];
    if (half == 0) {
        const float* kp = knn_x + (size_t)bg * 192 + jj * 6;
        lv[wave][jj] = make_float4(kp[3], kp[4], kp[5], 0.0f);
    }
    // producer and consumer are the same wave -> wave-local wait, no barrier
    asm volatile("s_waitcnt lgkmcnt(0)" ::: "memory");

    float accS[2] = {0.0f, 0.0f};   // sin^5 partial sums (this lane's k-subset)
    float accC[2] = {0.0f, 0.0f};   // cos^5 partial sums
    // lane (half,jj) handles k = 2*i + half
    const float4* myk = &lv[wave][half];
    #pragma unroll
    for (int i = 0; i < 16; ++i) {
        const float4 p = myk[2 * i];                  // broadcast ds_read_b128
        const float x = fmaf(e2, p.z, fmaf(e1, p.y, e0 * p.x));

        const float ts = FRACT(x);                    // revolutions in [0,1)
        const float tc = FRACT(x + 0.25f);
        const float s  = __builtin_amdgcn_sinf(ts);   // sin(2*pi*x)
        const float cc = __builtin_amdgcn_sinf(tc);   // cos(2*pi*x)
        const float s2 = s * s,  s4 = s2 * s2;
        const float q2 = cc * cc, q4 = q2 * q2;
        accS[i & 1] = fmaf(s4, s,  accS[i & 1]);      // += sin^5
        accC[i & 1] = fmaf(q4, cc, accC[i & 1]);      // += cos^5
    }

    // merge even-k / odd-k halves across the lane32 boundary
    const float aS = accS[0] + accS[1];
    const float aC = accC[0] + accC[1];
    const float totS = aS + __shfl_xor(aS, 32, 64);
    const float totC = aC + __shfl_xor(aC, 32, 64);
    // lane jj -> sin channel jj ; lane 32+jj -> cos channel 32+jj
    const float klraw = (half ? totC : totS) * 0.0625f;  // 2 * mean_k

    const size_t obase = ((size_t)b * 128) * 2048 + g;
    out[obase + (size_t)lane * 2048]        = klraw;   // normalized in pass 2
    out[obase + (size_t)(64 + lane) * 2048] = lcline;  // final
}

__global__ __launch_bounds__(256) void line_pass2(float* __restrict__ out)
{
    const int b = blockIdx.x >> 6;   // 0..7
    const int c = blockIdx.x & 63;   // 0..63
    float*       kl = out + ((size_t)b * 128 + c) * 2048;
    const float* ll = out + ((size_t)b * 128 + 64 + c) * 2048;

    float v[8];
    float ss = 0.0f;
    #pragma unroll
    for (int i = 0; i < 8; ++i) {
        v[i] = kl[threadIdx.x + i * 256];
        ss = fmaf(v[i], v[i], ss);
    }
    #pragma unroll
    for (int off = 32; off; off >>= 1) ss += __shfl_xor(ss, off, 64);

    __shared__ float wsum[4];
    if ((threadIdx.x & 63) == 0) wsum[threadIdx.x >> 6] = ss;
    __syncthreads();
    const float tot = wsum[0] + wsum[1] + wsum[2] + wsum[3];
    const float rn  = 1.0f / sqrtf(tot);

    #pragma unroll
    for (int i = 0; i < 8; ++i) {
        const int idx = threadIdx.x + i * 256;
        kl[idx] = fmaf(v[i], rn, -ll[idx]);
    }
}

extern "C" void kernel_launch(void* const* d_in, const int* in_sizes, int n_in,
                              void* d_out, int out_size, void* d_ws, size_t ws_size,
                              hipStream_t stream) {
    const float* lc_x  = (const float*)d_in[0];   // 8*2048*64
    const float* knn_x = (const float*)d_in[1];   // 8*2048*32*6
    const float* fB    = (const float*)d_in[2];   // 7*32
    float* out = (float*)d_out;                   // 8*128*2048

    line_pass1<<<4096, 256, 0, stream>>>(lc_x, knn_x, fB, out);
    line_pass2<<<512, 256, 0, stream>>>(out);
}